// Round 3
// baseline (336.493 us; speedup 1.0000x reference)
//
#include <hip/hip_runtime.h>
#include <hip/hip_bf16.h>

// TriMipEncoding: x[800000,3] f32, fm[3,512,512,16] f32 -> out[800000,48] f32
//
// R5 = R4 resubmit (R4 bench died in infra, no kernel signal).
// Strategy: R3's MLP-tripling was a perfect null => gather is latency-bound
// at the per-CU outstanding-request (MSHR) cap with ~0% L2 hit rate (FETCH ==
// demand bytes; 25 MB texture vs 4 MB per-XCD L2, random point order).
// Sustained rate = MSHRs / latency, so the only levers are fewer misses and
// lower latency — both delivered by processing points in 3D-Morton order:
// a contiguous curve window is a compact 3D blob whose THREE plane projections
// are all small tiles => in-flight texture working set fits per-XCD L2.
// Pipeline: fp16-convert | zero-hist, histogram(4096 Morton bins), prefix,
// scatter (sorted float4 records {x,y,z,orig_idx}), gather in sorted order
// with XCD-chunked blockIdx swizzle, writing out[orig_idx] (192 B aligned).

#define N_PTS 800000
#define PLANE 512
#define FDIM  16
#define FM_ELEMS (3 * PLANE * PLANE * FDIM)          // 12,582,912 floats
#define FMH_BYTES (FM_ELEMS * 2)                     // 25,165,824 B fp16
#define NBINS 4096                                   // 4 bits/dim Morton
#define HIST_BYTES (NBINS * 4)                       // 16,384 B
#define SORTED_BYTES (N_PTS * 16)                    // 12,800,000 B
#define WS_FMH_OFF 0
#define WS_HIST_OFF FMH_BYTES                        // 25,165,824 (16-aligned)
#define WS_SORT_OFF (FMH_BYTES + HIST_BYTES)         // 25,182,208 (16-aligned)
#define WS_TOTAL (WS_SORT_OFF + SORTED_BYTES)        // 37,982,208 B
#define GATHER_THREADS (N_PTS * 8)                   // 6,400,000
#define GATHER_BLOCKS (GATHER_THREADS / 256)         // 25,000 (div by 8)
#define PT_BLOCKS (N_PTS / 256)                      // 3,125 (exact)
#define TOTAL_F32 (N_PTS * 48)                       // fallback

typedef _Float16 half2v __attribute__((ext_vector_type(2)));
typedef _Float16 half4v __attribute__((ext_vector_type(4)));
typedef float    float2v __attribute__((ext_vector_type(2)));

__global__ __launch_bounds__(256) void convert_fp16_kernel(
    const float* __restrict__ fm, _Float16* __restrict__ fmh)
{
    unsigned t = blockIdx.x * blockDim.x + threadIdx.x;
    if (t >= (unsigned)(FM_ELEMS / 4)) return;
    float4 v = ((const float4*)fm)[t];
    half4v h;
    h.x = (_Float16)v.x; h.y = (_Float16)v.y;
    h.z = (_Float16)v.z; h.w = (_Float16)v.w;
    ((half4v*)fmh)[t] = h;
}

__global__ __launch_bounds__(256) void zero_hist_kernel(unsigned* __restrict__ hist)
{
    unsigned t = blockIdx.x * blockDim.x + threadIdx.x;
    if (t < NBINS) hist[t] = 0u;
}

__device__ __forceinline__ unsigned spread4(unsigned v)
{
    // 4 bits b3b2b1b0 -> bit positions 9,6,3,0
    return (v & 1u) | ((v & 2u) << 2) | ((v & 4u) << 4) | ((v & 8u) << 6);
}

__device__ __forceinline__ unsigned morton_key(float x0, float x1, float x2)
{
    int ix = min(max((int)(x0 * 16.0f), 0), 15);
    int iy = min(max((int)(x1 * 16.0f), 0), 15);
    int iz = min(max((int)(x2 * 16.0f), 0), 15);
    return spread4((unsigned)ix) | (spread4((unsigned)iy) << 1)
         | (spread4((unsigned)iz) << 2);
}

__global__ __launch_bounds__(256) void hist_kernel(
    const float* __restrict__ x, unsigned* __restrict__ hist)
{
    unsigned t = blockIdx.x * blockDim.x + threadIdx.x;  // 800,000 exact
    if (t >= (unsigned)N_PTS) return;
    float x0 = x[3u * t + 0u];
    float x1 = x[3u * t + 1u];
    float x2 = x[3u * t + 2u];
    atomicAdd(&hist[morton_key(x0, x1, x2)], 1u);
}

__global__ __launch_bounds__(1024) void prefix_kernel(unsigned* __restrict__ hist)
{
    __shared__ unsigned s[1024];
    unsigned t = threadIdx.x;                 // single block of 1024
    unsigned v0 = hist[4u * t + 0u];
    unsigned v1 = hist[4u * t + 1u];
    unsigned v2 = hist[4u * t + 2u];
    unsigned v3 = hist[4u * t + 3u];
    unsigned sum = v0 + v1 + v2 + v3;
    s[t] = sum;
    __syncthreads();
    for (unsigned off = 1u; off < 1024u; off <<= 1) {
        unsigned add = (t >= off) ? s[t - off] : 0u;
        __syncthreads();
        s[t] += add;
        __syncthreads();
    }
    unsigned base = s[t] - sum;               // exclusive prefix of this group
    hist[4u * t + 0u] = base;
    hist[4u * t + 1u] = base + v0;
    hist[4u * t + 2u] = base + v0 + v1;
    hist[4u * t + 3u] = base + v0 + v1 + v2;
}

__global__ __launch_bounds__(256) void scatter_kernel(
    const float* __restrict__ x, unsigned* __restrict__ hist,
    float4* __restrict__ sorted)
{
    unsigned t = blockIdx.x * blockDim.x + threadIdx.x;
    if (t >= (unsigned)N_PTS) return;
    float x0 = x[3u * t + 0u];
    float x1 = x[3u * t + 1u];
    float x2 = x[3u * t + 2u];
    unsigned pos = atomicAdd(&hist[morton_key(x0, x1, x2)], 1u);
    if (pos < (unsigned)N_PTS) {
        float4 rec;
        rec.x = x0; rec.y = x1; rec.z = x2; rec.w = __uint_as_float(t);
        sorted[pos] = rec;
    }
}

__global__ __launch_bounds__(256) void trimip_fp16_sorted_kernel(
    const float4* __restrict__ sorted,
    const _Float16* __restrict__ fmh,
    float* __restrict__ out)
{
    // XCD-chunked swizzle: XCD k works a contiguous chunk of sorted order.
    unsigned bid = blockIdx.x;
    unsigned swz = (bid & 7u) * (GATHER_BLOCKS / 8u) + (bid >> 3);
    unsigned t = swz * 256u + threadIdx.x;
    if (t >= (unsigned)GATHER_THREADS) return;

    unsigned c2 = t & 7u;            // channel pair {2*c2, 2*c2+1}
    unsigned s  = t >> 3;            // sorted position

    float4 rec = sorted[s];          // 8 lanes broadcast; wave reads contiguous
    float x0 = rec.x, x1 = rec.y, x2 = rec.z;
    unsigned n = __float_as_uint(rec.w);
    if (n >= (unsigned)N_PTS) return;

    // plane p coords: p=0 -> (y,z); p=1 -> (x,z); p=2 -> (x,y)
    float ua[3] = {x1, x0, x0};
    float va[3] = {x2, x2, x1};

    float fu[3], fv[3];
    unsigned o00[3], o01[3], o10[3], o11[3];

#pragma unroll
    for (int p = 0; p < 3; ++p) {
        float u = ua[p] * (float)PLANE - 0.5f;
        float v = va[p] * (float)PLANE - 0.5f;
        float i0f = floorf(u);
        float j0f = floorf(v);
        fu[p] = u - i0f;
        fv[p] = v - j0f;

        int i0 = (int)i0f;
        int j0 = (int)j0f;
        int i1 = min(max(i0 + 1, 0), PLANE - 1);
        int j1 = min(max(j0 + 1, 0), PLANE - 1);
        i0 = min(max(i0, 0), PLANE - 1);
        j0 = min(max(j0, 0), PLANE - 1);

        unsigned pb = (unsigned)p * (PLANE * PLANE * FDIM) + 2u * c2;
        o00[p] = pb + (unsigned)(j0 * PLANE + i0) * FDIM;
        o01[p] = pb + (unsigned)(j0 * PLANE + i1) * FDIM;
        o10[p] = pb + (unsigned)(j1 * PLANE + i0) * FDIM;
        o11[p] = pb + (unsigned)(j1 * PLANE + i1) * FDIM;
    }

    half2v h00[3], h01[3], h10[3], h11[3];
#pragma unroll
    for (int p = 0; p < 3; ++p) {
        h00[p] = *(const half2v*)(fmh + o00[p]);
        h01[p] = *(const half2v*)(fmh + o01[p]);
        h10[p] = *(const half2v*)(fmh + o10[p]);
        h11[p] = *(const half2v*)(fmh + o11[p]);
    }

    // out row n: [3 planes][16 ch]; unit writes 192 B contiguous (64B-aligned)
    float2v* ob = (float2v*)out + (size_t)n * 24u + c2;
#pragma unroll
    for (int p = 0; p < 3; ++p) {
        float2v r;
        {
            float t00 = (float)h00[p].x, t01 = (float)h01[p].x;
            float t10 = (float)h10[p].x, t11 = (float)h11[p].x;
            float r0 = t00 + fu[p] * (t01 - t00);
            float r1 = t10 + fu[p] * (t11 - t10);
            r.x = r0 + fv[p] * (r1 - r0);
        }
        {
            float t00 = (float)h00[p].y, t01 = (float)h01[p].y;
            float t10 = (float)h10[p].y, t11 = (float)h11[p].y;
            float r0 = t00 + fu[p] * (t01 - t00);
            float r1 = t10 + fu[p] * (t11 - t10);
            r.y = r0 + fv[p] * (r1 - r0);
        }
        __builtin_nontemporal_store(r, ob + (unsigned)p * 8u);
    }
}

// R3 fused kernel (fallback when ws fits fp16 texture but not the sort buffers)
__global__ __launch_bounds__(256) void trimip_fp16_fused_kernel(
    const float* __restrict__ x,
    const _Float16* __restrict__ fmh,
    float* __restrict__ out)
{
    unsigned t = blockIdx.x * blockDim.x + threadIdx.x;
    if (t >= (unsigned)GATHER_THREADS) return;

    unsigned c2 = t & 7u;
    unsigned n  = t >> 3;

    const float* xr = x + 3u * n;
    float x0 = xr[0], x1 = xr[1], x2 = xr[2];

    float ua[3] = {x1, x0, x0};
    float va[3] = {x2, x2, x1};

    float fu[3], fv[3];
    unsigned o00[3], o01[3], o10[3], o11[3];

#pragma unroll
    for (int p = 0; p < 3; ++p) {
        float u = ua[p] * (float)PLANE - 0.5f;
        float v = va[p] * (float)PLANE - 0.5f;
        float i0f = floorf(u);
        float j0f = floorf(v);
        fu[p] = u - i0f;
        fv[p] = v - j0f;

        int i0 = (int)i0f;
        int j0 = (int)j0f;
        int i1 = min(max(i0 + 1, 0), PLANE - 1);
        int j1 = min(max(j0 + 1, 0), PLANE - 1);
        i0 = min(max(i0, 0), PLANE - 1);
        j0 = min(max(j0, 0), PLANE - 1);

        unsigned pb = (unsigned)p * (PLANE * PLANE * FDIM) + 2u * c2;
        o00[p] = pb + (unsigned)(j0 * PLANE + i0) * FDIM;
        o01[p] = pb + (unsigned)(j0 * PLANE + i1) * FDIM;
        o10[p] = pb + (unsigned)(j1 * PLANE + i0) * FDIM;
        o11[p] = pb + (unsigned)(j1 * PLANE + i1) * FDIM;
    }

    half2v h00[3], h01[3], h10[3], h11[3];
#pragma unroll
    for (int p = 0; p < 3; ++p) {
        h00[p] = *(const half2v*)(fmh + o00[p]);
        h01[p] = *(const half2v*)(fmh + o01[p]);
        h10[p] = *(const half2v*)(fmh + o10[p]);
        h11[p] = *(const half2v*)(fmh + o11[p]);
    }

    float2v* ob = (float2v*)out + (size_t)n * 24u + c2;
#pragma unroll
    for (int p = 0; p < 3; ++p) {
        float2v r;
        {
            float t00 = (float)h00[p].x, t01 = (float)h01[p].x;
            float t10 = (float)h10[p].x, t11 = (float)h11[p].x;
            float r0 = t00 + fu[p] * (t01 - t00);
            float r1 = t10 + fu[p] * (t11 - t10);
            r.x = r0 + fv[p] * (r1 - r0);
        }
        {
            float t00 = (float)h00[p].y, t01 = (float)h01[p].y;
            float t10 = (float)h10[p].y, t11 = (float)h11[p].y;
            float r0 = t00 + fu[p] * (t01 - t00);
            float r1 = t10 + fu[p] * (t11 - t10);
            r.y = r0 + fv[p] * (r1 - r0);
        }
        __builtin_nontemporal_store(r, ob + (unsigned)p * 8u);
    }
}

// Fallback (proven R1 kernel) if ws_size can't hold the fp16 texture.
__global__ __launch_bounds__(256) void trimip_f32_kernel(
    const float* __restrict__ x,
    const float* __restrict__ fm,
    float* __restrict__ out)
{
    unsigned t = blockIdx.x * blockDim.x + threadIdx.x;
    if (t >= (unsigned)TOTAL_F32) return;

    unsigned c    = t & 15u;
    unsigned unit = t >> 4;
    unsigned n    = unit / 3u;
    unsigned p    = unit - n * 3u;

    unsigned iu = (p == 0u) ? 1u : 0u;
    unsigned iv = (p == 2u) ? 1u : 2u;

    float a = x[n * 3u + iu];
    float b = x[n * 3u + iv];

    float u = a * (float)PLANE - 0.5f;
    float v = b * (float)PLANE - 0.5f;
    float i0f = floorf(u);
    float j0f = floorf(v);
    float fu = u - i0f;
    float fv = v - j0f;

    int i0 = (int)i0f;
    int j0 = (int)j0f;
    int i1 = min(max(i0 + 1, 0), PLANE - 1);
    int j1 = min(max(j0 + 1, 0), PLANE - 1);
    i0 = min(max(i0, 0), PLANE - 1);
    j0 = min(max(j0, 0), PLANE - 1);

    const float* base = fm + (size_t)p * (PLANE * PLANE * FDIM);
    float t00 = base[((size_t)(j0 * PLANE + i0)) * FDIM + c];
    float t01 = base[((size_t)(j0 * PLANE + i1)) * FDIM + c];
    float t10 = base[((size_t)(j1 * PLANE + i0)) * FDIM + c];
    float t11 = base[((size_t)(j1 * PLANE + i1)) * FDIM + c];

    float r0 = t00 + fu * (t01 - t00);
    float r1 = t10 + fu * (t11 - t10);
    float r  = r0 + fv * (r1 - r0);

    __builtin_nontemporal_store(r, &out[t]);
}

extern "C" void kernel_launch(void* const* d_in, const int* in_sizes, int n_in,
                              void* d_out, int out_size, void* d_ws, size_t ws_size,
                              hipStream_t stream)
{
    const float* x  = (const float*)d_in[0];
    const float* fm = (const float*)d_in[1];
    float* out      = (float*)d_out;

    if (ws_size >= (size_t)WS_TOTAL) {
        char* ws = (char*)d_ws;
        _Float16* fmh  = (_Float16*)(ws + WS_FMH_OFF);
        unsigned* hist = (unsigned*)(ws + WS_HIST_OFF);
        float4*  sorted = (float4*)(ws + WS_SORT_OFF);

        convert_fp16_kernel<<<FM_ELEMS / 4 / 256, 256, 0, stream>>>(fm, fmh);
        zero_hist_kernel<<<NBINS / 256, 256, 0, stream>>>(hist);
        hist_kernel<<<PT_BLOCKS, 256, 0, stream>>>(x, hist);
        prefix_kernel<<<1, 1024, 0, stream>>>(hist);
        scatter_kernel<<<PT_BLOCKS, 256, 0, stream>>>(x, hist, sorted);
        trimip_fp16_sorted_kernel<<<GATHER_BLOCKS, 256, 0, stream>>>(sorted, fmh, out);
    } else if (ws_size >= (size_t)FMH_BYTES) {
        _Float16* fmh = (_Float16*)d_ws;
        convert_fp16_kernel<<<FM_ELEMS / 4 / 256, 256, 0, stream>>>(fm, fmh);
        trimip_fp16_fused_kernel<<<(GATHER_THREADS + 255) / 256, 256, 0, stream>>>(x, fmh, out);
    } else {
        trimip_f32_kernel<<<(TOTAL_F32 + 255) / 256, 256, 0, stream>>>(x, fm, out);
    }
}

// Round 6
// 297.643 us; speedup vs baseline: 1.1305x; 1.1305x over previous
//
#include <hip/hip_runtime.h>
#include <hip/hip_bf16.h>

// TriMipEncoding: x[800000,3] f32, fm[3,512,512,16] f32 -> out[800000,48] f32
//
// R8 = R6/R7 content, finally submitted intact.
// Strategy: R5 proved Morton-order gather works (gather fell out of top-5,
// i.e. <88us vs 117us unsorted) but the 4-pass counting sort cost ~80-110us
// and net-regressed (336us). R8 keeps the locality, kills the sort overhead:
//   K1 convert fp16 (+ zero 4097 bin counters inline, null-guarded)
//   K2 single-pass capacity-bucket scatter: 4096-cell Morton key, fixed 256
//      slots/bin, atomicAdd counter, overflow spill list
//   K3 gather over slot regions (idle slots exit block-uniformly) + overflow
//      tail, XCD-chunked block swizzle, out[orig_idx] 192B-aligned writes.
// Eliminated vs R5: hist pass (full x read + 800K atomics), 1-block prefix
// scan, zero_hist launch => 3 dispatches instead of 6.

#define N_PTS 800000
#define PLANE 512
#define FDIM  16
#define FM_ELEMS (3 * PLANE * PLANE * FDIM)          // 12,582,912 floats
#define FMH_BYTES (FM_ELEMS * 2)                     // 25,165,824 B fp16
#define NBINS 4096                                   // 4 bits/dim Morton
#define CAP 256                                      // slots per bin (pow2)
#define OVF_CAP 131072                               // overflow records
#define MAIN_UNITS (NBINS * CAP)                     // 1,048,576
#define GATHER_UNITS (MAIN_UNITS + OVF_CAP)          // 1,179,648
#define GATHER2_THREADS (GATHER_UNITS * 8)           // 9,437,184
#define GATHER2_BLOCKS (GATHER2_THREADS / 256)       // 36,864 (= 8 * 4608)

#define WS_FMH_OFF 0
#define WS_CNT_OFF FMH_BYTES                         // 25,165,824 (4096*4 B)
#define WS_OVFCNT_OFF (WS_CNT_OFF + NBINS * 4)       // 25,182,208 (4 B)
#define WS_SLOT_OFF (WS_OVFCNT_OFF + 16)             // 25,182,224 (16-aligned)
#define WS_OVF_OFF (WS_SLOT_OFF + MAIN_UNITS * 16)   // 41,959,440 (16-aligned)
#define WS_TOTAL (WS_OVF_OFF + OVF_CAP * 16)         // 44,056,592 B

#define GATHER_THREADS (N_PTS * 8)                   // 6,400,000 (fallback R3)
#define PT_BLOCKS (N_PTS / 256)                      // 3,125 (exact)
#define TOTAL_F32 (N_PTS * 48)                       // fallback R1

typedef _Float16 half2v __attribute__((ext_vector_type(2)));
typedef _Float16 half4v __attribute__((ext_vector_type(4)));
typedef float    float2v __attribute__((ext_vector_type(2)));

__global__ __launch_bounds__(256) void convert_fp16_zero_kernel(
    const float* __restrict__ fm, _Float16* __restrict__ fmh,
    unsigned* __restrict__ cntz)   // cnt[0..4095] ++ ovfcnt at [4096]; may be null
{
    unsigned t = blockIdx.x * blockDim.x + threadIdx.x;
    if (cntz != (unsigned*)0 && blockIdx.x == 0) {
        for (unsigned z = threadIdx.x; z < (unsigned)(NBINS + 1); z += 256u)
            cntz[z] = 0u;
    }
    if (t >= (unsigned)(FM_ELEMS / 4)) return;
    float4 v = ((const float4*)fm)[t];
    half4v h;
    h.x = (_Float16)v.x; h.y = (_Float16)v.y;
    h.z = (_Float16)v.z; h.w = (_Float16)v.w;
    ((half4v*)fmh)[t] = h;
}

__device__ __forceinline__ unsigned spread4(unsigned v)
{
    // 4 bits b3b2b1b0 -> bit positions 9,6,3,0
    return (v & 1u) | ((v & 2u) << 2) | ((v & 4u) << 4) | ((v & 8u) << 6);
}

__device__ __forceinline__ unsigned morton_key(float x0, float x1, float x2)
{
    int ix = min(max((int)(x0 * 16.0f), 0), 15);
    int iy = min(max((int)(x1 * 16.0f), 0), 15);
    int iz = min(max((int)(x2 * 16.0f), 0), 15);
    return spread4((unsigned)ix) | (spread4((unsigned)iy) << 1)
         | (spread4((unsigned)iz) << 2);
}

__global__ __launch_bounds__(256) void scatter_direct_kernel(
    const float* __restrict__ x, unsigned* __restrict__ cnt,
    unsigned* __restrict__ ovfcnt,
    float4* __restrict__ slots, float4* __restrict__ ovf)
{
    unsigned t = blockIdx.x * blockDim.x + threadIdx.x;
    if (t >= (unsigned)N_PTS) return;
    float x0 = x[3u * t + 0u];
    float x1 = x[3u * t + 1u];
    float x2 = x[3u * t + 2u];
    unsigned key = morton_key(x0, x1, x2);
    unsigned pos = atomicAdd(&cnt[key], 1u);
    float4 rec;
    rec.x = x0; rec.y = x1; rec.z = x2; rec.w = __uint_as_float(t);
    if (pos < (unsigned)CAP) {
        slots[key * CAP + pos] = rec;
    } else {
        unsigned o = atomicAdd(ovfcnt, 1u);
        if (o < (unsigned)OVF_CAP) ovf[o] = rec;
    }
}

__global__ __launch_bounds__(256) void trimip_fp16_bucket_kernel(
    const float4* __restrict__ slots,
    const float4* __restrict__ ovf,
    const unsigned* __restrict__ cnt,
    const unsigned* __restrict__ ovfcnt,
    const _Float16* __restrict__ fmh,
    float* __restrict__ out)
{
    // XCD-chunked swizzle: XCD k works a contiguous chunk of Morton order.
    unsigned bid = blockIdx.x;
    unsigned swz = (bid & 7u) * (GATHER2_BLOCKS / 8u) + (bid >> 3);
    unsigned t = swz * 256u + threadIdx.x;

    unsigned c2 = t & 7u;            // channel pair {2*c2, 2*c2+1}
    unsigned u  = t >> 3;            // slot unit

    float4 rec;
    if (u < (unsigned)MAIN_UNITS) {
        unsigned bin  = u >> 8;      // CAP = 256
        unsigned slot = u & 255u;
        unsigned c = cnt[bin];
        if (c > (unsigned)CAP) c = (unsigned)CAP;
        if (slot >= c) return;       // idle slots exit early (block-coherent)
        rec = slots[u];
    } else {
        unsigned ou = u - (unsigned)MAIN_UNITS;
        unsigned oc = *ovfcnt;
        if (oc > (unsigned)OVF_CAP) oc = (unsigned)OVF_CAP;
        if (ou >= oc) return;
        rec = ovf[ou];
    }

    float x0 = rec.x, x1 = rec.y, x2 = rec.z;
    unsigned n = __float_as_uint(rec.w);
    if (n >= (unsigned)N_PTS) return;

    // plane p coords: p=0 -> (y,z); p=1 -> (x,z); p=2 -> (x,y)
    float ua[3] = {x1, x0, x0};
    float va[3] = {x2, x2, x1};

    float fu[3], fv[3];
    unsigned o00[3], o01[3], o10[3], o11[3];

#pragma unroll
    for (int p = 0; p < 3; ++p) {
        float u_ = ua[p] * (float)PLANE - 0.5f;
        float v_ = va[p] * (float)PLANE - 0.5f;
        float i0f = floorf(u_);
        float j0f = floorf(v_);
        fu[p] = u_ - i0f;
        fv[p] = v_ - j0f;

        int i0 = (int)i0f;
        int j0 = (int)j0f;
        int i1 = min(max(i0 + 1, 0), PLANE - 1);
        int j1 = min(max(j0 + 1, 0), PLANE - 1);
        i0 = min(max(i0, 0), PLANE - 1);
        j0 = min(max(j0, 0), PLANE - 1);

        unsigned pb = (unsigned)p * (PLANE * PLANE * FDIM) + 2u * c2;
        o00[p] = pb + (unsigned)(j0 * PLANE + i0) * FDIM;
        o01[p] = pb + (unsigned)(j0 * PLANE + i1) * FDIM;
        o10[p] = pb + (unsigned)(j1 * PLANE + i0) * FDIM;
        o11[p] = pb + (unsigned)(j1 * PLANE + i1) * FDIM;
    }

    half2v h00[3], h01[3], h10[3], h11[3];
#pragma unroll
    for (int p = 0; p < 3; ++p) {
        h00[p] = *(const half2v*)(fmh + o00[p]);
        h01[p] = *(const half2v*)(fmh + o01[p]);
        h10[p] = *(const half2v*)(fmh + o10[p]);
        h11[p] = *(const half2v*)(fmh + o11[p]);
    }

    // out row n: [3 planes][16 ch]; unit writes 192 B contiguous (64B-aligned)
    float2v* ob = (float2v*)out + (size_t)n * 24u + c2;
#pragma unroll
    for (int p = 0; p < 3; ++p) {
        float2v r;
        {
            float t00 = (float)h00[p].x, t01 = (float)h01[p].x;
            float t10 = (float)h10[p].x, t11 = (float)h11[p].x;
            float r0 = t00 + fu[p] * (t01 - t00);
            float r1 = t10 + fu[p] * (t11 - t10);
            r.x = r0 + fv[p] * (r1 - r0);
        }
        {
            float t00 = (float)h00[p].y, t01 = (float)h01[p].y;
            float t10 = (float)h10[p].y, t11 = (float)h11[p].y;
            float r0 = t00 + fu[p] * (t01 - t00);
            float r1 = t10 + fu[p] * (t11 - t10);
            r.y = r0 + fv[p] * (r1 - r0);
        }
        __builtin_nontemporal_store(r, ob + (unsigned)p * 8u);
    }
}

// R3 fused kernel (fallback when ws fits fp16 texture but not the buckets)
__global__ __launch_bounds__(256) void trimip_fp16_fused_kernel(
    const float* __restrict__ x,
    const _Float16* __restrict__ fmh,
    float* __restrict__ out)
{
    unsigned t = blockIdx.x * blockDim.x + threadIdx.x;
    if (t >= (unsigned)GATHER_THREADS) return;

    unsigned c2 = t & 7u;
    unsigned n  = t >> 3;

    const float* xr = x + 3u * n;
    float x0 = xr[0], x1 = xr[1], x2 = xr[2];

    float ua[3] = {x1, x0, x0};
    float va[3] = {x2, x2, x1};

    float fu[3], fv[3];
    unsigned o00[3], o01[3], o10[3], o11[3];

#pragma unroll
    for (int p = 0; p < 3; ++p) {
        float u = ua[p] * (float)PLANE - 0.5f;
        float v = va[p] * (float)PLANE - 0.5f;
        float i0f = floorf(u);
        float j0f = floorf(v);
        fu[p] = u - i0f;
        fv[p] = v - j0f;

        int i0 = (int)i0f;
        int j0 = (int)j0f;
        int i1 = min(max(i0 + 1, 0), PLANE - 1);
        int j1 = min(max(j0 + 1, 0), PLANE - 1);
        i0 = min(max(i0, 0), PLANE - 1);
        j0 = min(max(j0, 0), PLANE - 1);

        unsigned pb = (unsigned)p * (PLANE * PLANE * FDIM) + 2u * c2;
        o00[p] = pb + (unsigned)(j0 * PLANE + i0) * FDIM;
        o01[p] = pb + (unsigned)(j0 * PLANE + i1) * FDIM;
        o10[p] = pb + (unsigned)(j1 * PLANE + i0) * FDIM;
        o11[p] = pb + (unsigned)(j1 * PLANE + i1) * FDIM;
    }

    half2v h00[3], h01[3], h10[3], h11[3];
#pragma unroll
    for (int p = 0; p < 3; ++p) {
        h00[p] = *(const half2v*)(fmh + o00[p]);
        h01[p] = *(const half2v*)(fmh + o01[p]);
        h10[p] = *(const half2v*)(fmh + o10[p]);
        h11[p] = *(const half2v*)(fmh + o11[p]);
    }

    float2v* ob = (float2v*)out + (size_t)n * 24u + c2;
#pragma unroll
    for (int p = 0; p < 3; ++p) {
        float2v r;
        {
            float t00 = (float)h00[p].x, t01 = (float)h01[p].x;
            float t10 = (float)h10[p].x, t11 = (float)h11[p].x;
            float r0 = t00 + fu[p] * (t01 - t00);
            float r1 = t10 + fu[p] * (t11 - t10);
            r.x = r0 + fv[p] * (r1 - r0);
        }
        {
            float t00 = (float)h00[p].y, t01 = (float)h01[p].y;
            float t10 = (float)h10[p].y, t11 = (float)h11[p].y;
            float r0 = t00 + fu[p] * (t01 - t00);
            float r1 = t10 + fu[p] * (t11 - t10);
            r.y = r0 + fv[p] * (r1 - r0);
        }
        __builtin_nontemporal_store(r, ob + (unsigned)p * 8u);
    }
}

// Fallback (proven R1 kernel) if ws_size can't hold the fp16 texture.
__global__ __launch_bounds__(256) void trimip_f32_kernel(
    const float* __restrict__ x,
    const float* __restrict__ fm,
    float* __restrict__ out)
{
    unsigned t = blockIdx.x * blockDim.x + threadIdx.x;
    if (t >= (unsigned)TOTAL_F32) return;

    unsigned c    = t & 15u;
    unsigned unit = t >> 4;
    unsigned n    = unit / 3u;
    unsigned p    = unit - n * 3u;

    unsigned iu = (p == 0u) ? 1u : 0u;
    unsigned iv = (p == 2u) ? 1u : 2u;

    float a = x[n * 3u + iu];
    float b = x[n * 3u + iv];

    float u = a * (float)PLANE - 0.5f;
    float v = b * (float)PLANE - 0.5f;
    float i0f = floorf(u);
    float j0f = floorf(v);
    float fu = u - i0f;
    float fv = v - j0f;

    int i0 = (int)i0f;
    int j0 = (int)j0f;
    int i1 = min(max(i0 + 1, 0), PLANE - 1);
    int j1 = min(max(j0 + 1, 0), PLANE - 1);
    i0 = min(max(i0, 0), PLANE - 1);
    j0 = min(max(j0, 0), PLANE - 1);

    const float* base = fm + (size_t)p * (PLANE * PLANE * FDIM);
    float t00 = base[((size_t)(j0 * PLANE + i0)) * FDIM + c];
    float t01 = base[((size_t)(j0 * PLANE + i1)) * FDIM + c];
    float t10 = base[((size_t)(j1 * PLANE + i0)) * FDIM + c];
    float t11 = base[((size_t)(j1 * PLANE + i1)) * FDIM + c];

    float r0 = t00 + fu * (t01 - t00);
    float r1 = t10 + fu * (t11 - t10);
    float r  = r0 + fv * (r1 - r0);

    __builtin_nontemporal_store(r, &out[t]);
}

extern "C" void kernel_launch(void* const* d_in, const int* in_sizes, int n_in,
                              void* d_out, int out_size, void* d_ws, size_t ws_size,
                              hipStream_t stream)
{
    const float* x  = (const float*)d_in[0];
    const float* fm = (const float*)d_in[1];
    float* out      = (float*)d_out;

    if (ws_size >= (size_t)WS_TOTAL) {
        char* ws = (char*)d_ws;
        _Float16* fmh   = (_Float16*)(ws + WS_FMH_OFF);
        unsigned* cnt   = (unsigned*)(ws + WS_CNT_OFF);
        unsigned* ovfc  = (unsigned*)(ws + WS_OVFCNT_OFF);
        float4*   slots = (float4*)(ws + WS_SLOT_OFF);
        float4*   ovf   = (float4*)(ws + WS_OVF_OFF);

        convert_fp16_zero_kernel<<<FM_ELEMS / 4 / 256, 256, 0, stream>>>(fm, fmh, cnt);
        scatter_direct_kernel<<<PT_BLOCKS, 256, 0, stream>>>(x, cnt, ovfc, slots, ovf);
        trimip_fp16_bucket_kernel<<<GATHER2_BLOCKS, 256, 0, stream>>>(
            slots, ovf, cnt, ovfc, fmh, out);
    } else if (ws_size >= (size_t)FMH_BYTES) {
        _Float16* fmh = (_Float16*)d_ws;
        convert_fp16_zero_kernel<<<FM_ELEMS / 4 / 256, 256, 0, stream>>>(fm, fmh, (unsigned*)0);
        trimip_fp16_fused_kernel<<<(GATHER_THREADS + 255) / 256, 256, 0, stream>>>(x, fmh, out);
    } else {
        trimip_f32_kernel<<<(TOTAL_F32 + 255) / 256, 256, 0, stream>>>(x, fm, out);
    }
}